// Round 2
// baseline (2132.461 us; speedup 1.0000x reference)
//
#include <hip/hip_runtime.h>
#include <math.h>

typedef unsigned short u16;
typedef __attribute__((ext_vector_type(8))) short short8;
typedef __attribute__((ext_vector_type(4))) float floatx4;

#define Hh 16
#define Mm 1024
#define Dd 512
#define Oo 512
#define Nn 16384

__device__ __forceinline__ float b2f(u16 u) { return __uint_as_float(((unsigned)u) << 16); }
__device__ __forceinline__ u16 f2b(float f) {
    unsigned v = __float_as_uint(f);
    v += 0x7fffu + ((v >> 16) & 1u);
    return (u16)(v >> 16);
}
__device__ __forceinline__ short8 cvt8(const float* p) {
    float4 a = *(const float4*)p, b = *(const float4*)(p + 4);
    u16 o[8];
    o[0] = f2b(a.x); o[1] = f2b(a.y); o[2] = f2b(a.z); o[3] = f2b(a.w);
    o[4] = f2b(b.x); o[5] = f2b(b.y); o[6] = f2b(b.z); o[7] = f2b(b.w);
    return *(short8*)o;
}

// ---------------------------------------------------------------------------
// Generic GEMM-BT: C[h][m][n] = sum_k A[h][m][k] * B[h][n][k] (+ bias[h][n])
// A,B row-major, contraction along fast axis; each may be fp32 or bf16
// (converted to bf16 during LDS staging). bias fp32. C fp32 or bf16.
// block 256 (4 waves), tile 64x64, K step 64. MFMA 16x16x32 bf16.
// ---------------------------------------------------------------------------
__global__ __launch_bounds__(256) void gemm_bt(
    const void* __restrict__ A, const void* __restrict__ B, const float* __restrict__ bias,
    void* __restrict__ C, int K, int lda, int ldb, int ldc,
    long sA, long sB, long sBias, long sC, int aF32, int bF32, int outBf)
{
    __shared__ u16 At[64][72];   // +8 pad: row stride 144B -> 2-way max (free)
    __shared__ u16 Bt[64][72];
    const int tid = threadIdx.x, lane = tid & 63, wid = tid >> 6;
    const int m0 = blockIdx.y * 64, n0 = blockIdx.x * 64;
    const int h = blockIdx.z;
    const int wm = wid >> 1, wn = wid & 1;
    const int rl = lane & 15, rq = (lane >> 4) * 4, gl8 = (lane >> 4) * 8;

    floatx4 zero4 = {0.f, 0.f, 0.f, 0.f};
    floatx4 acc[2][2];
    acc[0][0] = zero4; acc[0][1] = zero4; acc[1][0] = zero4; acc[1][1] = zero4;

    for (int k0 = 0; k0 < K; k0 += 64) {
#pragma unroll
        for (int i = 0; i < 2; i++) {
            int c = tid + i * 256;
            int r = c >> 3, cc = (c & 7) * 8;
            long aoff = (long)h * sA + (long)(m0 + r) * lda + k0 + cc;
            long boff = (long)h * sB + (long)(n0 + r) * ldb + k0 + cc;
            *(short8*)&At[r][cc] = aF32 ? cvt8((const float*)A + aoff)
                                        : *(const short8*)((const u16*)A + aoff);
            *(short8*)&Bt[r][cc] = bF32 ? cvt8((const float*)B + boff)
                                        : *(const short8*)((const u16*)B + boff);
        }
        __syncthreads();
#pragma unroll
        for (int ks = 0; ks < 2; ks++) {
            short8 a0 = *(const short8*)&At[wm * 32 + rl][ks * 32 + gl8];
            short8 a1 = *(const short8*)&At[wm * 32 + 16 + rl][ks * 32 + gl8];
            short8 b0 = *(const short8*)&Bt[wn * 32 + rl][ks * 32 + gl8];
            short8 b1 = *(const short8*)&Bt[wn * 32 + 16 + rl][ks * 32 + gl8];
            acc[0][0] = __builtin_amdgcn_mfma_f32_16x16x32_bf16(a0, b0, acc[0][0], 0, 0, 0);
            acc[0][1] = __builtin_amdgcn_mfma_f32_16x16x32_bf16(a0, b1, acc[0][1], 0, 0, 0);
            acc[1][0] = __builtin_amdgcn_mfma_f32_16x16x32_bf16(a1, b0, acc[1][0], 0, 0, 0);
            acc[1][1] = __builtin_amdgcn_mfma_f32_16x16x32_bf16(a1, b1, acc[1][1], 0, 0, 0);
        }
        __syncthreads();
    }

#pragma unroll
    for (int i = 0; i < 2; i++)
#pragma unroll
        for (int j = 0; j < 2; j++) {
            int col = n0 + wn * 32 + j * 16 + rl;
            float bb = bias ? bias[(long)h * sBias + col] : 0.f;
#pragma unroll
            for (int r = 0; r < 4; r++) {
                int row = m0 + wm * 32 + i * 16 + rq + r;
                long idx = (long)h * sC + (long)row * ldc + col;
                float v = acc[i][j][r] + bb;
                if (outBf) ((u16*)C)[idx] = f2b(v);
                else       ((float*)C)[idx] = v;
            }
        }
}

// ---------------------------------------------------------------------------
// Row softmax: rows of 512 fp32 logits -> bf16 probabilities. One wave/row.
// ---------------------------------------------------------------------------
__global__ __launch_bounds__(256) void softmax_rows(const float* __restrict__ L, u16* __restrict__ Kout)
{
    const int tid = threadIdx.x, lane = tid & 63, wid = tid >> 6;
    const long row = (long)blockIdx.x * 4 + wid;
    const float* p = L + row * 512 + lane * 8;
    float v[8];
    *(float4*)&v[0] = *(const float4*)p;
    *(float4*)&v[4] = *(const float4*)(p + 4);
    float mx = v[0];
#pragma unroll
    for (int i = 1; i < 8; i++) mx = fmaxf(mx, v[i]);
    for (int d = 1; d < 64; d <<= 1) mx = fmaxf(mx, __shfl_xor(mx, d));
    float s = 0.f;
#pragma unroll
    for (int i = 0; i < 8; i++) { v[i] = __expf(v[i] - mx); s += v[i]; }
    for (int d = 1; d < 64; d <<= 1) s += __shfl_xor(s, d);
    float inv = 1.f / s;
    u16 o[8];
#pragma unroll
    for (int i = 0; i < 8; i++) o[i] = f2b(v[i] * inv);
    *(short8*)(Kout + row * 512 + lane * 8) = *(short8*)o;
}

// ---------------------------------------------------------------------------
// Fused flash attention over heads:
//   out[n][o] = bf[o] + sum_h sum_m softmax_m(kq[n].key_h[m]) * vpt[h][o][m]
// kq fp32 (converted on Q-tile load), key/vpt bf16, out fp32.
// Block: 32 query rows x full O=512, 512 threads (8 waves), loops 16 heads.
// ---------------------------------------------------------------------------
#define LDQ 520     // kq row stride (1040B = 260dw = 4 mod 32 -> 2-way, free)
#define LDP 1032    // P row stride (2064B = 516dw = 4 mod 32)
#define STW 2560    // per-wave staging region (u16)
#define FLASH_LDS ((32 * LDQ + 32 * LDP + 8 * STW) * 2 + 128)

__global__ __launch_bounds__(512) void flash(
    const float* __restrict__ kq, const u16* __restrict__ key,
    const u16* __restrict__ vpt, const float* __restrict__ bfv, float* __restrict__ out)
{
    extern __shared__ u16 sm[];
    u16* kq_s = sm;                       // [32][LDQ]
    u16* P = sm + 32 * LDQ;               // [32][LDP]
    u16* stg = P + 32 * LDP;              // 8 x STW
    float* lrow = (float*)(stg + 8 * STW);// [32]

    const int tid = threadIdx.x, lane = tid & 63, wid = tid >> 6;
    const int n0 = blockIdx.x * 32;
    const int rl = lane & 15, rq = (lane >> 4) * 4, gl8 = (lane >> 4) * 8;
    u16* stw = stg + wid * STW;

    // load+convert query tile [32][512] fp32 -> bf16 LDS
#pragma unroll
    for (int i = 0; i < 4; i++) {
        int c = tid + i * 512;            // 2048 chunks of 8
        int r = c >> 6, cc = (c & 63) * 8;
        *(short8*)&kq_s[r * LDQ + cc] = cvt8(&kq[(long)(n0 + r) * 512 + cc]);
    }
    __syncthreads();

    floatx4 zero4 = {0.f, 0.f, 0.f, 0.f};
    floatx4 oacc[2][4];
#pragma unroll
    for (int i = 0; i < 2; i++)
#pragma unroll
        for (int j = 0; j < 4; j++) oacc[i][j] = zero4;

    for (int h = 0; h < Hh; h++) {
        if (tid < 32) lrow[tid] = 0.f;
        __syncthreads();
        const u16* keyh = key + (long)h * Mm * Oo;
        const u16* vph = vpt + (long)h * Oo * Mm;

        // ---- S phase: P[0:32][m] = exp(kq_tile . key_h[m]) , lrow = rowsums --
        for (int mc = 0; mc < 8; mc++) {
            int m0 = mc * 128;
            floatx4 s0 = zero4, s1 = zero4;
#pragma unroll
            for (int oc = 0; oc < 4; oc++) {
                // stage this wave's 16 key rows x 128 contraction columns
#pragma unroll
                for (int j = 0; j < 4; j++) {
                    int c = lane + j * 64;
                    int r = c >> 4, cc = (c & 15) * 8;
                    *(short8*)&stw[r * 136 + cc] =
                        *(const short8*)&keyh[(long)(m0 + wid * 16 + r) * 512 + oc * 128 + cc];
                }
#pragma unroll
                for (int ks = 0; ks < 4; ks++) {
                    int ko = oc * 128 + ks * 32;
                    short8 b = *(const short8*)&stw[rl * 136 + ks * 32 + gl8];
                    short8 a0 = *(const short8*)&kq_s[rl * LDQ + ko + gl8];
                    short8 a1 = *(const short8*)&kq_s[(16 + rl) * LDQ + ko + gl8];
                    s0 = __builtin_amdgcn_mfma_f32_16x16x32_bf16(a0, b, s0, 0, 0, 0);
                    s1 = __builtin_amdgcn_mfma_f32_16x16x32_bf16(a1, b, s1, 0, 0, 0);
                }
            }
            // exp (bounded: |s| <= max|k| ~ 5.6), row-sums, P write
            float e0[4], e1[4], t0[4], t1[4];
#pragma unroll
            for (int r = 0; r < 4; r++) {
                e0[r] = __expf(s0[r]); t0[r] = e0[r];
                e1[r] = __expf(s1[r]); t1[r] = e1[r];
            }
            for (int d = 1; d < 16; d <<= 1) {
#pragma unroll
                for (int r = 0; r < 4; r++) {
                    t0[r] += __shfl_xor(t0[r], d);
                    t1[r] += __shfl_xor(t1[r], d);
                }
            }
            if (rl == 0) {
#pragma unroll
                for (int r = 0; r < 4; r++) {
                    atomicAdd(&lrow[rq + r], t0[r]);
                    atomicAdd(&lrow[16 + rq + r], t1[r]);
                }
            }
            int colP = m0 + wid * 16 + rl;
#pragma unroll
            for (int r = 0; r < 4; r++) {
                P[(rq + r) * LDP + colP] = f2b(e0[r]);
                P[(16 + rq + r) * LDP + colP] = f2b(e1[r]);
            }
        }
        __syncthreads();
        if (tid < 32) lrow[tid] = 1.f / lrow[tid];
        __syncthreads();
        // normalize P in place
#pragma unroll
        for (int i = 0; i < 8; i++) {
            int c = tid + i * 512;        // 4096 chunks of 8 (32 rows x 128)
            int r = c >> 7, cc = (c & 127) * 8;
            float inv = lrow[r];
            u16* pp = &P[r * LDP + cc];
            short8 v = *(short8*)pp;
            u16 o[8];
#pragma unroll
            for (int q = 0; q < 8; q++) o[q] = f2b(b2f(((u16*)&v)[q]) * inv);
            *(short8*)pp = *(short8*)o;
        }
        __syncthreads();

        // ---- PV phase: oacc += P @ V'_h^T ; wave owns o-cols [wid*64,+64) ---
        for (int pc = 0; pc < 32; pc++) {
            int m0 = pc * 32;
            // stage vpt[h][wid*64 .. +64][m0 .. +32] (wave-private)
#pragma unroll
            for (int j = 0; j < 4; j++) {
                int c = lane + j * 64;
                int r = c >> 2, cc = (c & 3) * 8;
                *(short8*)&stw[r * 40 + cc] =
                    *(const short8*)&vph[(long)(wid * 64 + r) * 1024 + m0 + cc];
            }
            short8 a0 = *(const short8*)&P[rl * LDP + m0 + gl8];
            short8 a1 = *(const short8*)&P[(16 + rl) * LDP + m0 + gl8];
#pragma unroll
            for (int to = 0; to < 4; to++) {
                short8 b = *(const short8*)&stw[(to * 16 + rl) * 40 + gl8];
                oacc[0][to] = __builtin_amdgcn_mfma_f32_16x16x32_bf16(a0, b, oacc[0][to], 0, 0, 0);
                oacc[1][to] = __builtin_amdgcn_mfma_f32_16x16x32_bf16(a1, b, oacc[1][to], 0, 0, 0);
            }
        }
        __syncthreads();   // all PV reads of P done before next head rewrites it
    }

    // epilogue: out[n][col] = oacc + bf[col]  (fp32 store)
#pragma unroll
    for (int tn = 0; tn < 2; tn++)
#pragma unroll
        for (int to = 0; to < 4; to++) {
            int col = wid * 64 + to * 16 + rl;
            float add = bfv[col];
#pragma unroll
            for (int r = 0; r < 4; r++) {
                int row = n0 + tn * 16 + rq + r;
                out[(long)row * 512 + col] = oacc[tn][to][r] + add;
            }
        }
}

// ---------------------------------------------------------------------------
extern "C" void kernel_launch(void* const* d_in, const int* in_sizes, int n_in,
                              void* d_out, int out_size, void* d_ws, size_t ws_size,
                              hipStream_t stream)
{
    const float* k    = (const float*)d_in[0];   // [N][O] fp32
    const void*  mems = d_in[1];                 // [H][M][D] fp32
    const void*  Wk   = d_in[2];                 // [H][O][D] fp32
    const float* bk   = (const float*)d_in[3];   // [H][O] fp32
    const void*  Wv   = d_in[4];                 // [H][O][D] fp32
    const float* bv   = (const float*)d_in[5];   // [H][O] fp32
    const void*  Wf   = d_in[6];                 // [O][H*O] fp32
    const float* bfv  = (const float*)d_in[7];   // [O] fp32
    float* out = (float*)d_out;

    char* ws = (char*)d_ws;
    float* logits = (float*)ws;                                   // H*M*O fp32 = 32 MB
    u16* keyb = (u16*)(ws + (size_t)Hh * Mm * Oo * 4);            // H*M*O bf16 = 16 MB
    u16* valb = keyb + (size_t)Hh * Mm * Oo;                      // 16 MB
    u16* vptb = valb + (size_t)Hh * Mm * Oo;                      // V'^T [H][O][M], 16 MB

    // key logits: [h][m][o] = mems_h @ Wk_h^T + bk_h   (fp32 out)
    gemm_bt<<<dim3(8, 16, 16), 256, 0, stream>>>(
        mems, Wk, bk, logits, 512, 512, 512, 512,
        (long)Mm * Dd, (long)Oo * Dd, 512L, (long)Mm * Oo, 1, 1, 0);

    // mem_key = softmax(logits) -> bf16
    softmax_rows<<<dim3(Hh * Mm / 4), 256, 0, stream>>>(logits, keyb);

    // val: [h][m][o] = mems_h @ Wv_h^T + bv_h   (bf16 out)
    gemm_bt<<<dim3(8, 16, 16), 256, 0, stream>>>(
        mems, Wv, bv, valb, 512, 512, 512, 512,
        (long)Mm * Dd, (long)Oo * Dd, 512L, (long)Mm * Oo, 1, 1, 1);

    // V'^T: [h][o][m] = Wf[:, h*O:(h+1)*O] @ val_h^T   (bf16 out, transposed)
    gemm_bt<<<dim3(16, 8, 16), 256, 0, stream>>>(
        Wf, valb, nullptr, vptb, 512, Hh * Oo, 512, 1024,
        512L, (long)Mm * Oo, 0L, (long)Oo * Mm, 1, 0, 1);

    // fused attention over all heads, final projection pre-folded into V'
    flash<<<dim3(Nn / 32), 512, FLASH_LDS, stream>>>(k, keyb, vptb, bfv, out);
}

// Round 3
// 1468.226 us; speedup vs baseline: 1.4524x; 1.4524x over previous
//
#include <hip/hip_runtime.h>
#include <math.h>

typedef unsigned short u16;
typedef __attribute__((ext_vector_type(8))) short short8;
typedef __attribute__((ext_vector_type(4))) float floatx4;

#define Hh 16
#define Mm 1024
#define Dd 512
#define Oo 512
#define Nn 16384

__device__ __forceinline__ float b2f(u16 u) { return __uint_as_float(((unsigned)u) << 16); }
__device__ __forceinline__ u16 f2b(float f) {
    unsigned v = __float_as_uint(f);
    v += 0x7fffu + ((v >> 16) & 1u);
    return (u16)(v >> 16);
}
__device__ __forceinline__ short8 cvt8(const float* p) {
    float4 a = *(const float4*)p, b = *(const float4*)(p + 4);
    u16 o[8];
    o[0] = f2b(a.x); o[1] = f2b(a.y); o[2] = f2b(a.z); o[3] = f2b(a.w);
    o[4] = f2b(b.x); o[5] = f2b(b.y); o[6] = f2b(b.z); o[7] = f2b(b.w);
    return *(short8*)o;
}

// ---------------------------------------------------------------------------
// Generic GEMM-BT: C[h][m][n] = sum_k A[h][m][k] * B[h][n][k] (+ bias[h][n])
// ---------------------------------------------------------------------------
__global__ __launch_bounds__(256) void gemm_bt(
    const void* __restrict__ A, const void* __restrict__ B, const float* __restrict__ bias,
    void* __restrict__ C, int K, int lda, int ldb, int ldc,
    long sA, long sB, long sBias, long sC, int aF32, int bF32, int outBf)
{
    __shared__ u16 At[64][72];
    __shared__ u16 Bt[64][72];
    const int tid = threadIdx.x, lane = tid & 63, wid = tid >> 6;
    const int m0 = blockIdx.y * 64, n0 = blockIdx.x * 64;
    const int h = blockIdx.z;
    const int wm = wid >> 1, wn = wid & 1;
    const int rl = lane & 15, rq = (lane >> 4) * 4, gl8 = (lane >> 4) * 8;

    floatx4 zero4 = {0.f, 0.f, 0.f, 0.f};
    floatx4 acc[2][2];
    acc[0][0] = zero4; acc[0][1] = zero4; acc[1][0] = zero4; acc[1][1] = zero4;

    for (int k0 = 0; k0 < K; k0 += 64) {
#pragma unroll
        for (int i = 0; i < 2; i++) {
            int c = tid + i * 256;
            int r = c >> 3, cc = (c & 7) * 8;
            long aoff = (long)h * sA + (long)(m0 + r) * lda + k0 + cc;
            long boff = (long)h * sB + (long)(n0 + r) * ldb + k0 + cc;
            *(short8*)&At[r][cc] = aF32 ? cvt8((const float*)A + aoff)
                                        : *(const short8*)((const u16*)A + aoff);
            *(short8*)&Bt[r][cc] = bF32 ? cvt8((const float*)B + boff)
                                        : *(const short8*)((const u16*)B + boff);
        }
        __syncthreads();
#pragma unroll
        for (int ks = 0; ks < 2; ks++) {
            short8 a0 = *(const short8*)&At[wm * 32 + rl][ks * 32 + gl8];
            short8 a1 = *(const short8*)&At[wm * 32 + 16 + rl][ks * 32 + gl8];
            short8 b0 = *(const short8*)&Bt[wn * 32 + rl][ks * 32 + gl8];
            short8 b1 = *(const short8*)&Bt[wn * 32 + 16 + rl][ks * 32 + gl8];
            acc[0][0] = __builtin_amdgcn_mfma_f32_16x16x32_bf16(a0, b0, acc[0][0], 0, 0, 0);
            acc[0][1] = __builtin_amdgcn_mfma_f32_16x16x32_bf16(a0, b1, acc[0][1], 0, 0, 0);
            acc[1][0] = __builtin_amdgcn_mfma_f32_16x16x32_bf16(a1, b0, acc[1][0], 0, 0, 0);
            acc[1][1] = __builtin_amdgcn_mfma_f32_16x16x32_bf16(a1, b1, acc[1][1], 0, 0, 0);
        }
        __syncthreads();
    }

#pragma unroll
    for (int i = 0; i < 2; i++)
#pragma unroll
        for (int j = 0; j < 2; j++) {
            int col = n0 + wn * 32 + j * 16 + rl;
            float bb = bias ? bias[(long)h * sBias + col] : 0.f;
#pragma unroll
            for (int r = 0; r < 4; r++) {
                int row = m0 + wm * 32 + i * 16 + rq + r;
                long idx = (long)h * sC + (long)row * ldc + col;
                float v = acc[i][j][r] + bb;
                if (outBf) ((u16*)C)[idx] = f2b(v);
                else       ((float*)C)[idx] = v;
            }
        }
}

// ---------------------------------------------------------------------------
// Row softmax: rows of 512 fp32 logits -> bf16 probabilities. One wave/row.
// ---------------------------------------------------------------------------
__global__ __launch_bounds__(256) void softmax_rows(const float* __restrict__ L, u16* __restrict__ Kout)
{
    const int tid = threadIdx.x, lane = tid & 63, wid = tid >> 6;
    const long row = (long)blockIdx.x * 4 + wid;
    const float* p = L + row * 512 + lane * 8;
    float v[8];
    *(float4*)&v[0] = *(const float4*)p;
    *(float4*)&v[4] = *(const float4*)(p + 4);
    float mx = v[0];
#pragma unroll
    for (int i = 1; i < 8; i++) mx = fmaxf(mx, v[i]);
    for (int d = 1; d < 64; d <<= 1) mx = fmaxf(mx, __shfl_xor(mx, d));
    float s = 0.f;
#pragma unroll
    for (int i = 0; i < 8; i++) { v[i] = __expf(v[i] - mx); s += v[i]; }
    for (int d = 1; d < 64; d <<= 1) s += __shfl_xor(s, d);
    float inv = 1.f / s;
    u16 o[8];
#pragma unroll
    for (int i = 0; i < 8; i++) o[i] = f2b(v[i] * inv);
    *(short8*)(Kout + row * 512 + lane * 8) = *(short8*)o;
}

// ---------------------------------------------------------------------------
// Fused flash attention over heads, 64 queries/block, direct-global B-frags.
//   out[n][o] = bf[o] + sum_h (1/l_h[n]) sum_m exp(kq[n].key_h[m]) * vpt[h][o][m]
// 512 threads (8 waves). P split in m-halves [64][512]. No staging LDS.
// ---------------------------------------------------------------------------
#define LDQ 520     // Q row stride u16 (1040B = 260 dw = 4 mod 32)
#define LDP 520     // P-half row stride u16
#define FLASH_LDS ((64 * LDQ + 64 * LDP) * 2 + 2 * 64 * 4 + 16)

__global__ __launch_bounds__(512, 2) void flash(
    const float* __restrict__ kq, const u16* __restrict__ key,
    const u16* __restrict__ vpt, const float* __restrict__ bfv, float* __restrict__ out)
{
    extern __shared__ u16 sm[];
    u16* kq_s = sm;                            // [64][LDQ]
    u16* Ph = sm + 64 * LDQ;                   // [64][LDP]
    float* lbuf = (float*)(sm + 64 * (LDQ + LDP)); // [2][64]

    const int tid = threadIdx.x, lane = tid & 63, wid = tid >> 6;
    const int n0 = blockIdx.x * 64;
    const int rl = lane & 15, rq = (lane >> 4) * 4, gl8 = (lane >> 4) * 8;

    // load+convert query tile [64][512] fp32 -> bf16 LDS
#pragma unroll
    for (int i = 0; i < 8; i++) {
        int c = tid + i * 512;                 // 4096 chunks of 8
        int r = c >> 6, cc = (c & 63) * 8;
        *(short8*)&kq_s[r * LDQ + cc] = cvt8(&kq[(long)(n0 + r) * 512 + cc]);
    }
    if (tid < 128) lbuf[tid] = 0.f;
    __syncthreads();

    floatx4 zero4 = {0.f, 0.f, 0.f, 0.f};
    floatx4 oacc[4][4], utmp[4][4];
#pragma unroll
    for (int i = 0; i < 4; i++)
#pragma unroll
        for (int j = 0; j < 4; j++) { oacc[i][j] = zero4; utmp[i][j] = zero4; }

    for (int h = 0; h < Hh; h++) {
        const u16* keyh = key + (long)h * Mm * Oo;
        const u16* vph = vpt + (long)h * Oo * Mm;
        float* lcur = lbuf + (h & 1) * 64;
        float* lnxt = lbuf + ((h + 1) & 1) * 64;

        for (int hf = 0; hf < 2; hf++) {
            // ---- S phase: Ph[q][m'] = exp(kq[q] . key_h[hf*512+m']) ----
            float psum[4][4];
#pragma unroll
            for (int qt = 0; qt < 4; qt++)
#pragma unroll
                for (int r = 0; r < 4; r++) psum[qt][r] = 0.f;

            for (int t = 0; t < 4; t++) {
                int mb = hf * 512 + wid * 64 + t * 16;   // this wave's 16 m-rows
                const u16* bp = keyh + (long)(mb + rl) * 512 + gl8;
                floatx4 s[4];
#pragma unroll
                for (int qt = 0; qt < 4; qt++) s[qt] = zero4;
#pragma unroll
                for (int ks = 0; ks < 16; ks++) {
                    short8 b = *(const short8*)(bp + ks * 32);
#pragma unroll
                    for (int qt = 0; qt < 4; qt++) {
                        short8 a = *(const short8*)&kq_s[(qt * 16 + rl) * LDQ + ks * 32 + gl8];
                        s[qt] = __builtin_amdgcn_mfma_f32_16x16x32_bf16(a, b, s[qt], 0, 0, 0);
                    }
                }
                int colP = wid * 64 + t * 16 + rl;
#pragma unroll
                for (int qt = 0; qt < 4; qt++)
#pragma unroll
                    for (int r = 0; r < 4; r++) {
                        float e = __expf(s[qt][r]);   // |logit| <= max|kq| ~ 5.6
                        psum[qt][r] += e;
                        Ph[(qt * 16 + rq + r) * LDP + colP] = f2b(e);
                    }
            }
            // wave-level row-sum (over this wave's 64 m), then LDS atomic
            for (int d = 1; d < 16; d <<= 1)
#pragma unroll
                for (int qt = 0; qt < 4; qt++)
#pragma unroll
                    for (int r = 0; r < 4; r++) psum[qt][r] += __shfl_xor(psum[qt][r], d);
            if (rl == 0)
#pragma unroll
                for (int qt = 0; qt < 4; qt++)
#pragma unroll
                    for (int r = 0; r < 4; r++)
                        atomicAdd(&lcur[qt * 16 + rq + r], psum[qt][r]);
            if (hf == 0 && tid < 64) lnxt[tid] = 0.f;   // prep next head's l buffer
            __syncthreads();

            // ---- PV phase: utmp += Ph @ V'_h[:, hf-half]^T ----
            const u16* vbp[4];
#pragma unroll
            for (int ot = 0; ot < 4; ot++)
                vbp[ot] = vph + (long)(wid * 64 + ot * 16 + rl) * Mm + hf * 512 + gl8;
#pragma unroll 4
            for (int mk = 0; mk < 16; mk++) {
                short8 a[4], b[4];
#pragma unroll
                for (int qt = 0; qt < 4; qt++)
                    a[qt] = *(const short8*)&Ph[(qt * 16 + rl) * LDP + mk * 32 + gl8];
#pragma unroll
                for (int ot = 0; ot < 4; ot++)
                    b[ot] = *(const short8*)(vbp[ot] + mk * 32);
#pragma unroll
                for (int qt = 0; qt < 4; qt++)
#pragma unroll
                    for (int ot = 0; ot < 4; ot++)
                        utmp[qt][ot] = __builtin_amdgcn_mfma_f32_16x16x32_bf16(a[qt], b[ot], utmp[qt][ot], 0, 0, 0);
            }

            if (hf == 1) {
                // scale per-head contribution by 1/l and fold into oacc
#pragma unroll
                for (int qt = 0; qt < 4; qt++)
#pragma unroll
                    for (int r = 0; r < 4; r++) {
                        float inv = 1.f / lcur[qt * 16 + rq + r];
#pragma unroll
                        for (int ot = 0; ot < 4; ot++) {
                            oacc[qt][ot][r] += inv * utmp[qt][ot][r];
                            utmp[qt][ot][r] = 0.f;
                        }
                    }
            }
            __syncthreads();   // Ph reads done before next S overwrites; lcur reads done
        }
    }

    // epilogue: out[n][col] = oacc + bf[col]  (fp32 store)
#pragma unroll
    for (int qt = 0; qt < 4; qt++)
#pragma unroll
        for (int ot = 0; ot < 4; ot++) {
            int col = wid * 64 + ot * 16 + rl;
            float add = bfv[col];
#pragma unroll
            for (int r = 0; r < 4; r++) {
                int row = n0 + qt * 16 + rq + r;
                out[(long)row * 512 + col] = oacc[qt][ot][r] + add;
            }
        }
}

// ---------------------------------------------------------------------------
extern "C" void kernel_launch(void* const* d_in, const int* in_sizes, int n_in,
                              void* d_out, int out_size, void* d_ws, size_t ws_size,
                              hipStream_t stream)
{
    const float* k    = (const float*)d_in[0];   // [N][O] fp32
    const void*  mems = d_in[1];                 // [H][M][D] fp32
    const void*  Wk   = d_in[2];                 // [H][O][D] fp32
    const float* bk   = (const float*)d_in[3];   // [H][O] fp32
    const void*  Wv   = d_in[4];                 // [H][O][D] fp32
    const float* bv   = (const float*)d_in[5];   // [H][O] fp32
    const void*  Wf   = d_in[6];                 // [O][H*O] fp32
    const float* bfv  = (const float*)d_in[7];   // [O] fp32
    float* out = (float*)d_out;

    char* ws = (char*)d_ws;
    float* logits = (float*)ws;                                   // H*M*O fp32 = 32 MB
    u16* keyb = (u16*)(ws + (size_t)Hh * Mm * Oo * 4);            // H*M*O bf16 = 16 MB
    u16* valb = keyb + (size_t)Hh * Mm * Oo;                      // 16 MB
    u16* vptb = valb + (size_t)Hh * Mm * Oo;                      // V'^T [H][O][M], 16 MB

    // key logits: [h][m][o] = mems_h @ Wk_h^T + bk_h   (fp32 out)
    gemm_bt<<<dim3(8, 16, 16), 256, 0, stream>>>(
        mems, Wk, bk, logits, 512, 512, 512, 512,
        (long)Mm * Dd, (long)Oo * Dd, 512L, (long)Mm * Oo, 1, 1, 0);

    // mem_key = softmax(logits) -> bf16
    softmax_rows<<<dim3(Hh * Mm / 4), 256, 0, stream>>>(logits, keyb);

    // val: [h][m][o] = mems_h @ Wv_h^T + bv_h   (bf16 out)
    gemm_bt<<<dim3(8, 16, 16), 256, 0, stream>>>(
        mems, Wv, bv, valb, 512, 512, 512, 512,
        (long)Mm * Dd, (long)Oo * Dd, 512L, (long)Mm * Oo, 1, 1, 1);

    // V'^T: [h][o][m] = Wf[:, h*O:(h+1)*O] @ val_h^T   (bf16 out, transposed)
    gemm_bt<<<dim3(16, 8, 16), 256, 0, stream>>>(
        Wf, valb, nullptr, vptb, 512, Hh * Oo, 512, 1024,
        512L, (long)Mm * Oo, 0L, (long)Oo * Mm, 1, 0, 1);

    // fused attention over all heads, final projection pre-folded into V'
    flash<<<dim3(Nn / 64), 512, FLASH_LDS, stream>>>(k, keyb, vptb, bfv, out);
}